// Round 1
// baseline (3243.965 us; speedup 1.0000x reference)
//
#include <hip/hip_runtime.h>

#define N_NODES  50000
#define N_EDGES  800000
#define NSC      32
#define XD       96
#define HID      128
#define MSG      256
#define LDA      264   // msg tile stride (bf16 elems), 256+8 pad, keeps 16B align
#define LDH      136   // h tile stride (bf16 elems), 128+8 pad
#define LDXO     68    // x_out rot-part stride (fp32 elems), 64+4 pad

typedef __bf16 bf16x8 __attribute__((ext_vector_type(8)));
typedef float  f32x4  __attribute__((ext_vector_type(4)));
typedef unsigned short u16x8 __attribute__((ext_vector_type(8)));

__device__ __forceinline__ unsigned short f2bf(float f) {
    union { float f; unsigned int u; } v; v.f = f;
    unsigned int u = v.u;
    return (unsigned short)((u + 0x7FFFu + ((u >> 16) & 1u)) >> 16);
}

// Transpose + bf16-convert the weights once per call.
// W1T[n][k] = bf16(W1[k][n])  (128 x 256), W2T[n][k] = bf16(W2[k][n]) (96 x 128)
__global__ void prep_weights(const float* __restrict__ W1, const float* __restrict__ W2,
                             unsigned short* __restrict__ W1T, unsigned short* __restrict__ W2T) {
    int i = blockIdx.x * 256 + threadIdx.x;
    if (i < 256 * 128) { int n = i >> 8; int k = i & 255; W1T[i] = f2bf(W1[k * 128 + n]); }
    if (i < 128 * 96)  { int n = i >> 7; int k = i & 127; W2T[i] = f2bf(W2[k * 96  + n]); }
}

__global__ __launch_bounds__(256, 2)
void eq_main(const float* __restrict__ x_scalar, const float* __restrict__ x_rot,
             const int* __restrict__ eidx, const float* __restrict__ dist,
             const float* __restrict__ rot,
             const unsigned short* __restrict__ W1T, const float* __restrict__ b1,
             const unsigned short* __restrict__ W2T, const float* __restrict__ b2,
             float* __restrict__ out_scalar, float* __restrict__ out_rot)
{
    __shared__ union { unsigned short A[64 * LDA]; float XO[64 * LDXO]; } uA;
    __shared__ unsigned short H[64 * LDH];
    __shared__ int colidx[64];
    __shared__ float b1s[HID];
    __shared__ float b2s[XD];

    const int tid = threadIdx.x;
    const int e0  = blockIdx.x * 64;

    if (tid < HID) b1s[tid] = b1[tid];
    if (tid < XD)  b2s[tid] = b2[tid];

    // ---------------- stage 1: build msg tile (bf16) in uA.A -----------------
    // msg row layout: [x_scalar[col] 0:32 | rotinv(x_rot[col]) 32:96 |
    //                  x_scalar[row] 96:128 | rotinv(x_rot[row]) 128:192 | dist 192:256]
    {
        const int eL = tid >> 2, p = tid & 3;
        const int e  = e0 + eL;
        if (e < N_EDGES) {
            const int r = eidx[e];
            const int c = eidx[N_EDGES + e];
            if (p == 0) colidx[eL] = c;
            unsigned short* dst = &uA.A[eL * LDA];

            if (p == 3) {
                // distance embedding: 64 floats -> dst[192:256]
                const float4* s = (const float4*)(dist + (size_t)e * 64);
                #pragma unroll
                for (int i = 0; i < 8; ++i) {
                    float4 v0 = s[2 * i], v1 = s[2 * i + 1];
                    u16x8 t = { f2bf(v0.x), f2bf(v0.y), f2bf(v0.z), f2bf(v0.w),
                                f2bf(v1.x), f2bf(v1.y), f2bf(v1.z), f2bf(v1.w) };
                    *(u16x8*)(dst + 192 + i * 8) = t;
                }
            } else {
                // rotation matrices for this edge (4 x 2 x 2)
                float rb[16];
                {
                    const float4* rp = (const float4*)(rot + (size_t)e * 16);
                    #pragma unroll
                    for (int i = 0; i < 4; ++i) ((float4*)rb)[i] = rp[i];
                }
                if (p == 0) {
                    // x_scalar[col] -> dst[0:32]
                    const float4* xs = (const float4*)(x_scalar + (size_t)c * NSC);
                    #pragma unroll
                    for (int i = 0; i < 4; ++i) {
                        float4 v0 = xs[2 * i], v1 = xs[2 * i + 1];
                        u16x8 t = { f2bf(v0.x), f2bf(v0.y), f2bf(v0.z), f2bf(v0.w),
                                    f2bf(v1.x), f2bf(v1.y), f2bf(v1.z), f2bf(v1.w) };
                        *(u16x8*)(dst + i * 8) = t;
                    }
                    // rotinv(x_rot[col]) reps 0..3 -> dst[32:64]
                    #pragma unroll
                    for (int j = 0; j < 4; ++j) {
                        const float4* xr = (const float4*)(x_rot + (size_t)c * 64 + j * 8);
                        float4 v0 = xr[0], v1 = xr[1];
                        float x[8] = { v0.x, v0.y, v0.z, v0.w, v1.x, v1.y, v1.z, v1.w };
                        u16x8 t;
                        #pragma unroll
                        for (int k = 0; k < 4; ++k) {
                            float a0 = x[2 * k], a1 = x[2 * k + 1];
                            t[2 * k]     = f2bf(a0 * rb[4 * k]     + a1 * rb[4 * k + 1]);
                            t[2 * k + 1] = f2bf(a0 * rb[4 * k + 2] + a1 * rb[4 * k + 3]);
                        }
                        *(u16x8*)(dst + 32 + j * 8) = t;
                    }
                } else if (p == 1) {
                    // rotinv(x_rot[col]) reps 4..7 -> dst[64:96]
                    #pragma unroll
                    for (int j = 0; j < 4; ++j) {
                        const float4* xr = (const float4*)(x_rot + (size_t)c * 64 + (j + 4) * 8);
                        float4 v0 = xr[0], v1 = xr[1];
                        float x[8] = { v0.x, v0.y, v0.z, v0.w, v1.x, v1.y, v1.z, v1.w };
                        u16x8 t;
                        #pragma unroll
                        for (int k = 0; k < 4; ++k) {
                            float a0 = x[2 * k], a1 = x[2 * k + 1];
                            t[2 * k]     = f2bf(a0 * rb[4 * k]     + a1 * rb[4 * k + 1]);
                            t[2 * k + 1] = f2bf(a0 * rb[4 * k + 2] + a1 * rb[4 * k + 3]);
                        }
                        *(u16x8*)(dst + 64 + j * 8) = t;
                    }
                    // x_scalar[row] -> dst[96:128]
                    const float4* xs = (const float4*)(x_scalar + (size_t)r * NSC);
                    #pragma unroll
                    for (int i = 0; i < 4; ++i) {
                        float4 v0 = xs[2 * i], v1 = xs[2 * i + 1];
                        u16x8 t = { f2bf(v0.x), f2bf(v0.y), f2bf(v0.z), f2bf(v0.w),
                                    f2bf(v1.x), f2bf(v1.y), f2bf(v1.z), f2bf(v1.w) };
                        *(u16x8*)(dst + 96 + i * 8) = t;
                    }
                } else { // p == 2
                    // rotinv(x_rot[row]) reps 0..7 -> dst[128:192]
                    #pragma unroll
                    for (int j = 0; j < 8; ++j) {
                        const float4* xr = (const float4*)(x_rot + (size_t)r * 64 + j * 8);
                        float4 v0 = xr[0], v1 = xr[1];
                        float x[8] = { v0.x, v0.y, v0.z, v0.w, v1.x, v1.y, v1.z, v1.w };
                        u16x8 t;
                        #pragma unroll
                        for (int k = 0; k < 4; ++k) {
                            float a0 = x[2 * k], a1 = x[2 * k + 1];
                            t[2 * k]     = f2bf(a0 * rb[4 * k]     + a1 * rb[4 * k + 1]);
                            t[2 * k + 1] = f2bf(a0 * rb[4 * k + 2] + a1 * rb[4 * k + 3]);
                        }
                        *(u16x8*)(dst + 128 + j * 8) = t;
                    }
                }
            }
        }
    }
    __syncthreads();

    // ---------------- stage 2: GEMM1  msg(64x256) @ W1(256x128) -> H --------
    const int lane = tid & 63, wave = tid >> 6;
    const int lrow = lane & 15, quad = lane >> 4;
    const int m0 = wave * 16;

    {
        f32x4 acc[8];
        #pragma unroll
        for (int j = 0; j < 8; ++j) acc[j] = (f32x4){0.f, 0.f, 0.f, 0.f};
        #pragma unroll
        for (int kk = 0; kk < 8; ++kk) {
            bf16x8 a = *(const bf16x8*)&uA.A[(m0 + lrow) * LDA + kk * 32 + quad * 8];
            const unsigned short* wb = W1T + (size_t)lrow * 256 + kk * 32 + quad * 8;
            #pragma unroll
            for (int j = 0; j < 8; ++j) {
                bf16x8 b = *(const bf16x8*)(wb + j * 16 * 256);
                acc[j] = __builtin_amdgcn_mfma_f32_16x16x32_bf16(a, b, acc[j], 0, 0, 0);
            }
        }
        // epilogue: bias + silu -> H (bf16)
        #pragma unroll
        for (int j = 0; j < 8; ++j) {
            const int n = j * 16 + lrow;
            const float bv = b1s[n];
            #pragma unroll
            for (int rr = 0; rr < 4; ++rr) {
                const int m = m0 + quad * 4 + rr;
                float v = acc[j][rr] + bv;
                float hv = v / (1.0f + __expf(-v));
                H[m * LDH + n] = f2bf(hv);
            }
        }
    }
    __syncthreads();

    // ---------------- stage 3: GEMM2  h(64x128) @ W2(128x96) ----------------
    {
        f32x4 acc2[6];
        #pragma unroll
        for (int j = 0; j < 6; ++j) acc2[j] = (f32x4){0.f, 0.f, 0.f, 0.f};
        #pragma unroll
        for (int kk = 0; kk < 4; ++kk) {
            bf16x8 a = *(const bf16x8*)&H[(m0 + lrow) * LDH + kk * 32 + quad * 8];
            const unsigned short* wb = W2T + (size_t)lrow * 128 + kk * 32 + quad * 8;
            #pragma unroll
            for (int j = 0; j < 6; ++j) {
                bf16x8 b = *(const bf16x8*)(wb + j * 16 * 128);
                acc2[j] = __builtin_amdgcn_mfma_f32_16x16x32_bf16(a, b, acc2[j], 0, 0, 0);
            }
        }
        // epilogue: scalar part -> atomics now; rot part -> LDS (reuse msg buf)
        #pragma unroll
        for (int j = 0; j < 6; ++j) {
            const int n = j * 16 + lrow;
            const float bv = b2s[n];
            #pragma unroll
            for (int rr = 0; rr < 4; ++rr) {
                const int m = m0 + quad * 4 + rr;
                float v = acc2[j][rr] + bv;
                if (j < 2) {  // n < 32: scalar message, no rotation
                    if (e0 + m < N_EDGES)
                        atomicAdd(&out_scalar[(size_t)colidx[m] * NSC + n], v);
                } else {
                    uA.XO[m * LDXO + (n - NSC)] = v;
                }
            }
        }
    }
    __syncthreads();

    // ---------------- stage 4: forward-rotate rot part + scatter ------------
    {
        const int eL = tid >> 2, p = tid & 3;
        const int e  = e0 + eL;
        if (e < N_EDGES) {
            const int c = colidx[eL];
            float rb[16];
            {
                const float4* rp = (const float4*)(rot + (size_t)e * 16);
                #pragma unroll
                for (int i = 0; i < 4; ++i) ((float4*)rb)[i] = rp[i];
            }
            const float* xo = &uA.XO[eL * LDXO];
            float* outp = out_rot + (size_t)c * 64;
            #pragma unroll
            for (int jj = 0; jj < 2; ++jj) {
                const int j = 2 * p + jj;
                #pragma unroll
                for (int k = 0; k < 4; ++k) {
                    float a0 = xo[j * 8 + k * 2], a1 = xo[j * 8 + k * 2 + 1];
                    // forward rotate: out[l] = a0*rot[k][0][l] + a1*rot[k][1][l]
                    atomicAdd(&outp[j * 8 + k * 2 + 0], a0 * rb[4 * k + 0] + a1 * rb[4 * k + 2]);
                    atomicAdd(&outp[j * 8 + k * 2 + 1], a0 * rb[4 * k + 1] + a1 * rb[4 * k + 3]);
                }
            }
        }
    }
}

extern "C" void kernel_launch(void* const* d_in, const int* in_sizes, int n_in,
                              void* d_out, int out_size, void* d_ws, size_t ws_size,
                              hipStream_t stream) {
    const float* x_scalar = (const float*)d_in[0];
    const float* x_rot    = (const float*)d_in[1];
    const int*   eidx     = (const int*)d_in[2];
    const float* dist     = (const float*)d_in[3];
    const float* rot      = (const float*)d_in[4];
    const float* W1       = (const float*)d_in[5];
    const float* b1       = (const float*)d_in[6];
    const float* W2       = (const float*)d_in[7];
    const float* b2       = (const float*)d_in[8];
    float* out = (float*)d_out;

    unsigned short* W1T = (unsigned short*)d_ws;            // 128*256 bf16
    unsigned short* W2T = W1T + 256 * 128;                  // 96*128 bf16

    hipMemsetAsync(d_out, 0, (size_t)out_size * sizeof(float), stream);
    prep_weights<<<128, 256, 0, stream>>>(W1, W2, W1T, W2T);
    eq_main<<<(N_EDGES + 63) / 64, 256, 0, stream>>>(
        x_scalar, x_rot, eidx, dist, rot, W1T, b1, W2T, b2,
        out, out + (size_t)N_NODES * NSC);
}

// Round 2
// 1043.709 us; speedup vs baseline: 3.1081x; 3.1081x over previous
//
#include <hip/hip_runtime.h>

#define N_NODES  50000
#define N_EDGES  800000
#define NSC      32
#define XD       96
#define HID      128
#define MSG      256
#define LDA      264   // msg tile stride (bf16 elems), 256+8 pad, keeps 16B align
#define LDH      136   // h tile stride (bf16 elems), 128+8 pad
#define LDXO     100   // x_out stride (fp32 elems), 96+4 pad
#define NBLK     196   // ceil(50000/256)

typedef __bf16 bf16x8 __attribute__((ext_vector_type(8)));
typedef float  f32x4  __attribute__((ext_vector_type(4)));
typedef unsigned short u16x8 __attribute__((ext_vector_type(8)));

__device__ __forceinline__ unsigned short f2bf(float f) {
    union { float f; unsigned int u; } v; v.f = f;
    unsigned int u = v.u;
    return (unsigned short)((u + 0x7FFFu + ((u >> 16) & 1u)) >> 16);
}
__device__ __forceinline__ float bflo(unsigned int u) {
    union { unsigned int u; float f; } v; v.u = u << 16; return v.f;
}
__device__ __forceinline__ float bfhi(unsigned int u) {
    union { unsigned int u; float f; } v; v.u = u & 0xffff0000u; return v.f;
}

// ---------------------------------------------------------------------------
// Weight prep: W1T[n][k] = bf16(W1[k][n]) (128x256), W2T[n][k] = bf16(W2[k][n])
__global__ void prep_weights(const float* __restrict__ W1, const float* __restrict__ W2,
                             unsigned short* __restrict__ W1T, unsigned short* __restrict__ W2T) {
    int i = blockIdx.x * 256 + threadIdx.x;
    if (i < 256 * 128) { int n = i >> 8; int k = i & 255; W1T[i] = f2bf(W1[k * 128 + n]); }
    if (i < 128 * 96)  { int n = i >> 7; int k = i & 127; W2T[i] = f2bf(W2[k * 96  + n]); }
}

// ---------------------------------------------------------------------------
// CSR build: histogram -> block scan -> top scan -> fixup -> rank
__global__ void hist_kernel(const int* __restrict__ eidx, int* __restrict__ cnt) {
    int e = blockIdx.x * 256 + threadIdx.x;
    if (e < N_EDGES) atomicAdd(&cnt[eidx[N_EDGES + e]], 1);
}

__global__ void scan_block(const int* __restrict__ cnt, int* __restrict__ start,
                           int* __restrict__ bsum) {
    __shared__ int tmp[256];
    const int t = threadIdx.x, i = blockIdx.x * 256 + t;
    int v = (i < N_NODES) ? cnt[i] : 0;
    tmp[t] = v; __syncthreads();
    #pragma unroll
    for (int off = 1; off < 256; off <<= 1) {
        int add = (t >= off) ? tmp[t - off] : 0;
        __syncthreads();
        tmp[t] += add;
        __syncthreads();
    }
    if (i < N_NODES) start[i] = tmp[t] - v;       // exclusive within block
    if (t == 255) bsum[blockIdx.x] = tmp[255];
}

__global__ void scan_top(const int* __restrict__ bsum, int* __restrict__ boff,
                         int* __restrict__ start) {
    __shared__ int tmp[256];
    const int t = threadIdx.x;
    int v = (t < NBLK) ? bsum[t] : 0;
    tmp[t] = v; __syncthreads();
    #pragma unroll
    for (int off = 1; off < 256; off <<= 1) {
        int add = (t >= off) ? tmp[t - off] : 0;
        __syncthreads();
        tmp[t] += add;
        __syncthreads();
    }
    if (t < NBLK) boff[t] = tmp[t] - v;
    if (t == 255) start[N_NODES] = tmp[255];      // = N_EDGES
}

__global__ void scan_fix(int* __restrict__ start, int* __restrict__ head,
                         const int* __restrict__ boff) {
    const int t = threadIdx.x, i = blockIdx.x * 256 + t;
    if (i < N_NODES) { int s = start[i] + boff[blockIdx.x]; start[i] = s; head[i] = s; }
}

__global__ void rank_kernel(const int* __restrict__ eidx, int* __restrict__ head,
                            int* __restrict__ pos) {
    int e = blockIdx.x * 256 + threadIdx.x;
    if (e < N_EDGES) pos[e] = atomicAdd(&head[eidx[N_EDGES + e]], 1);
}

// ---------------------------------------------------------------------------
// Main fused kernel. SORTED: write bf16 message rows at pos[e] (no atomics).
// !SORTED fallback: atomicAdd directly into outputs.
template <bool SORTED>
__global__ __launch_bounds__(256, 2)
void eq_main(const float* __restrict__ x_scalar, const float* __restrict__ x_rot,
             const int* __restrict__ eidx, const float* __restrict__ dist,
             const float* __restrict__ rot,
             const unsigned short* __restrict__ W1T, const float* __restrict__ b1,
             const unsigned short* __restrict__ W2T, const float* __restrict__ b2,
             float* __restrict__ out_scalar, float* __restrict__ out_rot,
             unsigned int* __restrict__ msg, const int* __restrict__ pos)
{
    __shared__ union { unsigned short A[64 * LDA]; float XO[64 * LDXO]; } uA;
    __shared__ unsigned short H[64 * LDH];
    __shared__ int colidx[64];
    __shared__ float b1s[HID];
    __shared__ float b2s[XD];

    const int tid = threadIdx.x;
    const int e0  = blockIdx.x * 64;

    if (tid < HID) b1s[tid] = b1[tid];
    if (tid < XD)  b2s[tid] = b2[tid];

    // ---------------- stage 1: build msg tile (bf16) in uA.A -----------------
    {
        const int eL = tid >> 2, p = tid & 3;
        const int e  = e0 + eL;
        if (e < N_EDGES) {
            const int r = eidx[e];
            const int c = eidx[N_EDGES + e];
            if (p == 0) colidx[eL] = c;
            unsigned short* dst = &uA.A[eL * LDA];

            if (p == 3) {
                const float4* s = (const float4*)(dist + (size_t)e * 64);
                #pragma unroll
                for (int i = 0; i < 8; ++i) {
                    float4 v0 = s[2 * i], v1 = s[2 * i + 1];
                    u16x8 t = { f2bf(v0.x), f2bf(v0.y), f2bf(v0.z), f2bf(v0.w),
                                f2bf(v1.x), f2bf(v1.y), f2bf(v1.z), f2bf(v1.w) };
                    *(u16x8*)(dst + 192 + i * 8) = t;
                }
            } else {
                float rb[16];
                {
                    const float4* rp = (const float4*)(rot + (size_t)e * 16);
                    #pragma unroll
                    for (int i = 0; i < 4; ++i) ((float4*)rb)[i] = rp[i];
                }
                if (p == 0) {
                    const float4* xs = (const float4*)(x_scalar + (size_t)c * NSC);
                    #pragma unroll
                    for (int i = 0; i < 4; ++i) {
                        float4 v0 = xs[2 * i], v1 = xs[2 * i + 1];
                        u16x8 t = { f2bf(v0.x), f2bf(v0.y), f2bf(v0.z), f2bf(v0.w),
                                    f2bf(v1.x), f2bf(v1.y), f2bf(v1.z), f2bf(v1.w) };
                        *(u16x8*)(dst + i * 8) = t;
                    }
                    #pragma unroll
                    for (int j = 0; j < 4; ++j) {
                        const float4* xr = (const float4*)(x_rot + (size_t)c * 64 + j * 8);
                        float4 v0 = xr[0], v1 = xr[1];
                        float x[8] = { v0.x, v0.y, v0.z, v0.w, v1.x, v1.y, v1.z, v1.w };
                        u16x8 t;
                        #pragma unroll
                        for (int k = 0; k < 4; ++k) {
                            float a0 = x[2 * k], a1 = x[2 * k + 1];
                            t[2 * k]     = f2bf(a0 * rb[4 * k]     + a1 * rb[4 * k + 1]);
                            t[2 * k + 1] = f2bf(a0 * rb[4 * k + 2] + a1 * rb[4 * k + 3]);
                        }
                        *(u16x8*)(dst + 32 + j * 8) = t;
                    }
                } else if (p == 1) {
                    #pragma unroll
                    for (int j = 0; j < 4; ++j) {
                        const float4* xr = (const float4*)(x_rot + (size_t)c * 64 + (j + 4) * 8);
                        float4 v0 = xr[0], v1 = xr[1];
                        float x[8] = { v0.x, v0.y, v0.z, v0.w, v1.x, v1.y, v1.z, v1.w };
                        u16x8 t;
                        #pragma unroll
                        for (int k = 0; k < 4; ++k) {
                            float a0 = x[2 * k], a1 = x[2 * k + 1];
                            t[2 * k]     = f2bf(a0 * rb[4 * k]     + a1 * rb[4 * k + 1]);
                            t[2 * k + 1] = f2bf(a0 * rb[4 * k + 2] + a1 * rb[4 * k + 3]);
                        }
                        *(u16x8*)(dst + 64 + j * 8) = t;
                    }
                    const float4* xs = (const float4*)(x_scalar + (size_t)r * NSC);
                    #pragma unroll
                    for (int i = 0; i < 4; ++i) {
                        float4 v0 = xs[2 * i], v1 = xs[2 * i + 1];
                        u16x8 t = { f2bf(v0.x), f2bf(v0.y), f2bf(v0.z), f2bf(v0.w),
                                    f2bf(v1.x), f2bf(v1.y), f2bf(v1.z), f2bf(v1.w) };
                        *(u16x8*)(dst + 96 + i * 8) = t;
                    }
                } else { // p == 2
                    #pragma unroll
                    for (int j = 0; j < 8; ++j) {
                        const float4* xr = (const float4*)(x_rot + (size_t)r * 64 + j * 8);
                        float4 v0 = xr[0], v1 = xr[1];
                        float x[8] = { v0.x, v0.y, v0.z, v0.w, v1.x, v1.y, v1.z, v1.w };
                        u16x8 t;
                        #pragma unroll
                        for (int k = 0; k < 4; ++k) {
                            float a0 = x[2 * k], a1 = x[2 * k + 1];
                            t[2 * k]     = f2bf(a0 * rb[4 * k]     + a1 * rb[4 * k + 1]);
                            t[2 * k + 1] = f2bf(a0 * rb[4 * k + 2] + a1 * rb[4 * k + 3]);
                        }
                        *(u16x8*)(dst + 128 + j * 8) = t;
                    }
                }
            }
        }
    }
    __syncthreads();

    // ---------------- stage 2: GEMM1  msg(64x256) @ W1(256x128) -> H --------
    const int lane = tid & 63, wave = tid >> 6;
    const int lrow = lane & 15, quad = lane >> 4;
    const int m0 = wave * 16;

    {
        f32x4 acc[8];
        #pragma unroll
        for (int j = 0; j < 8; ++j) acc[j] = (f32x4){0.f, 0.f, 0.f, 0.f};
        #pragma unroll
        for (int kk = 0; kk < 8; ++kk) {
            bf16x8 a = *(const bf16x8*)&uA.A[(m0 + lrow) * LDA + kk * 32 + quad * 8];
            const unsigned short* wb = W1T + (size_t)lrow * 256 + kk * 32 + quad * 8;
            #pragma unroll
            for (int j = 0; j < 8; ++j) {
                bf16x8 b = *(const bf16x8*)(wb + j * 16 * 256);
                acc[j] = __builtin_amdgcn_mfma_f32_16x16x32_bf16(a, b, acc[j], 0, 0, 0);
            }
        }
        #pragma unroll
        for (int j = 0; j < 8; ++j) {
            const int n = j * 16 + lrow;
            const float bv = b1s[n];
            #pragma unroll
            for (int rr = 0; rr < 4; ++rr) {
                const int m = m0 + quad * 4 + rr;
                float v = acc[j][rr] + bv;
                float hv = v / (1.0f + __expf(-v));
                H[m * LDH + n] = f2bf(hv);
            }
        }
    }
    __syncthreads();

    // ---------------- stage 3: GEMM2  h(64x128) @ W2(128x96) ----------------
    {
        f32x4 acc2[6];
        #pragma unroll
        for (int j = 0; j < 6; ++j) acc2[j] = (f32x4){0.f, 0.f, 0.f, 0.f};
        #pragma unroll
        for (int kk = 0; kk < 4; ++kk) {
            bf16x8 a = *(const bf16x8*)&H[(m0 + lrow) * LDH + kk * 32 + quad * 8];
            const unsigned short* wb = W2T + (size_t)lrow * 128 + kk * 32 + quad * 8;
            #pragma unroll
            for (int j = 0; j < 6; ++j) {
                bf16x8 b = *(const bf16x8*)(wb + j * 16 * 128);
                acc2[j] = __builtin_amdgcn_mfma_f32_16x16x32_bf16(a, b, acc2[j], 0, 0, 0);
            }
        }
        #pragma unroll
        for (int j = 0; j < 6; ++j) {
            const int n = j * 16 + lrow;
            const float bv = b2s[n];
            #pragma unroll
            for (int rr = 0; rr < 4; ++rr) {
                const int m = m0 + quad * 4 + rr;
                float v = acc2[j][rr] + bv;
                if (SORTED) {
                    uA.XO[m * LDXO + n] = v;
                } else {
                    if (j < 2) {
                        if (e0 + m < N_EDGES)
                            atomicAdd(&out_scalar[(size_t)colidx[m] * NSC + n], v);
                    } else {
                        uA.XO[m * LDXO + (n - NSC)] = v;
                    }
                }
            }
        }
    }
    __syncthreads();

    // ---------------- stage 4: forward-rotate + emit ------------------------
    {
        const int eL = tid >> 2, p = tid & 3;
        const int e  = e0 + eL;
        if (e < N_EDGES) {
            float rb[16];
            {
                const float4* rp = (const float4*)(rot + (size_t)e * 16);
                #pragma unroll
                for (int i = 0; i < 4; ++i) ((float4*)rb)[i] = rp[i];
            }
            if (SORTED) {
                const float* xo = &uA.XO[eL * LDXO];
                unsigned int buf[12];
                #pragma unroll
                for (int q = 0; q < 12; ++q) {
                    const int i = p * 24 + 2 * q;
                    float v0 = xo[i], v1 = xo[i + 1];
                    if (i >= NSC) {
                        const int k = ((i - NSC) >> 1) & 3;
                        float a0 = v0, a1 = v1;
                        v0 = a0 * rb[4 * k + 0] + a1 * rb[4 * k + 2];
                        v1 = a0 * rb[4 * k + 1] + a1 * rb[4 * k + 3];
                    }
                    buf[q] = (unsigned int)f2bf(v0) | ((unsigned int)f2bf(v1) << 16);
                }
                unsigned int* mrow = msg + (size_t)pos[e] * 48 + p * 12;
                *(uint4*)(mrow + 0) = *(uint4*)(buf + 0);
                *(uint4*)(mrow + 4) = *(uint4*)(buf + 4);
                *(uint4*)(mrow + 8) = *(uint4*)(buf + 8);
            } else {
                const int c = colidx[eL];
                const float* xo = &uA.XO[eL * LDXO];
                float* outp = out_rot + (size_t)c * 64;
                #pragma unroll
                for (int jj = 0; jj < 2; ++jj) {
                    const int j = 2 * p + jj;
                    #pragma unroll
                    for (int k = 0; k < 4; ++k) {
                        float a0 = xo[j * 8 + k * 2], a1 = xo[j * 8 + k * 2 + 1];
                        atomicAdd(&outp[j * 8 + k * 2 + 0], a0 * rb[4 * k + 0] + a1 * rb[4 * k + 2]);
                        atomicAdd(&outp[j * 8 + k * 2 + 1], a0 * rb[4 * k + 1] + a1 * rb[4 * k + 3]);
                    }
                }
            }
        }
    }
}

// ---------------------------------------------------------------------------
// Gather: one wave per node, stream contiguous sorted message rows, fp32 acc.
__global__ __launch_bounds__(256)
void gather_kernel(const unsigned int* __restrict__ msg, const int* __restrict__ start,
                   float* __restrict__ out_scalar, float* __restrict__ out_rot) {
    const int wave = threadIdx.x >> 6, lane = threadIdx.x & 63;
    const int n = blockIdx.x * 4 + wave;
    if (n >= N_NODES) return;
    const int s = start[n], e = start[n + 1];
    if (lane < 48) {
        float a0 = 0.f, a1 = 0.f;
        const unsigned int* p = msg + (size_t)s * 48 + lane;
        int i = s;
        for (; i + 1 < e; i += 2) {
            unsigned int u0 = p[0], u1 = p[48];
            p += 96;
            a0 += bflo(u0) + bflo(u1);
            a1 += bfhi(u0) + bfhi(u1);
        }
        if (i < e) { unsigned int u = p[0]; a0 += bflo(u); a1 += bfhi(u); }
        const int col = lane * 2;
        float2 r = make_float2(a0, a1);
        if (col < NSC) *(float2*)(out_scalar + (size_t)n * NSC + col) = r;
        else           *(float2*)(out_rot   + (size_t)n * 64 + (col - NSC)) = r;
    }
}

// ---------------------------------------------------------------------------
extern "C" void kernel_launch(void* const* d_in, const int* in_sizes, int n_in,
                              void* d_out, int out_size, void* d_ws, size_t ws_size,
                              hipStream_t stream) {
    const float* x_scalar = (const float*)d_in[0];
    const float* x_rot    = (const float*)d_in[1];
    const int*   eidx     = (const int*)d_in[2];
    const float* dist     = (const float*)d_in[3];
    const float* rot      = (const float*)d_in[4];
    const float* W1       = (const float*)d_in[5];
    const float* b1       = (const float*)d_in[6];
    const float* W2       = (const float*)d_in[7];
    const float* b2       = (const float*)d_in[8];
    float* out        = (float*)d_out;
    float* out_rot    = out + (size_t)N_NODES * NSC;

    // workspace bump allocator (256B aligned)
    uintptr_t base = (uintptr_t)d_ws;
    auto alloc = [&](size_t bytes) {
        uintptr_t p = base; base += (bytes + 255) & ~(size_t)255; return p;
    };
    unsigned short* W1T  = (unsigned short*)alloc(256 * 128 * 2);
    unsigned short* W2T  = (unsigned short*)alloc(128 * 96 * 2);
    int*            cnt  = (int*)alloc(N_NODES * 4);
    int*            start= (int*)alloc((N_NODES + 1) * 4);
    int*            head = (int*)alloc(N_NODES * 4);
    int*            bsum = (int*)alloc(NBLK * 4);
    int*            boff = (int*)alloc(NBLK * 4);
    int*            pos  = (int*)alloc((size_t)N_EDGES * 4);
    unsigned int*   msg  = (unsigned int*)alloc((size_t)N_EDGES * 48 * 4);
    const size_t needed = base - (uintptr_t)d_ws;

    prep_weights<<<128, 256, 0, stream>>>(W1, W2, W1T, W2T);

    if (ws_size >= needed) {
        hipMemsetAsync(cnt, 0, N_NODES * 4, stream);
        hist_kernel<<<N_EDGES / 256, 256, 0, stream>>>(eidx, cnt);
        scan_block<<<NBLK, 256, 0, stream>>>(cnt, start, bsum);
        scan_top<<<1, 256, 0, stream>>>(bsum, boff, start);
        scan_fix<<<NBLK, 256, 0, stream>>>(start, head, boff);
        rank_kernel<<<N_EDGES / 256, 256, 0, stream>>>(eidx, head, pos);
        eq_main<true><<<N_EDGES / 64, 256, 0, stream>>>(
            x_scalar, x_rot, eidx, dist, rot, W1T, b1, W2T, b2,
            out, out_rot, msg, pos);
        gather_kernel<<<(N_NODES + 3) / 4, 256, 0, stream>>>(msg, start, out, out_rot);
    } else {
        // fallback: atomic scatter (R1 behavior)
        hipMemsetAsync(d_out, 0, (size_t)out_size * sizeof(float), stream);
        eq_main<false><<<N_EDGES / 64, 256, 0, stream>>>(
            x_scalar, x_rot, eidx, dist, rot, W1T, b1, W2T, b2,
            out, out_rot, nullptr, nullptr);
    }
}